// Round 7
// baseline (615.876 us; speedup 1.0000x reference)
//
#include <hip/hip_runtime.h>

typedef unsigned short u16;
typedef unsigned int u32;
typedef __bf16 bf16x8 __attribute__((ext_vector_type(8)));
typedef float f32x4 __attribute__((ext_vector_type(4)));
typedef u16 u16x8 __attribute__((ext_vector_type(8)));

#define NTOK 8192
#define CDIM 1024
#define NEXP 8
#define FEDIM 1024
#define FSDIM 4096

#define GLD16(gp, lp) __builtin_amdgcn_global_load_lds( \
    (const __attribute__((address_space(1))) void*)(gp), \
    (__attribute__((address_space(3))) void*)(lp), 16, 0, 0)

__device__ __forceinline__ u16 f2bf(float f) {
  u32 u = __float_as_uint(f);
  u += 0x7FFFu + ((u >> 16) & 1u);   // RNE
  return (u16)(u >> 16);
}

// ---------------- gate: scores, softmax, top-2, expert lists, x->bf16 -------
__global__ __launch_bounds__(256) void gate_kernel(
    const float* __restrict__ x, const float* __restrict__ gw,
    float* __restrict__ scores, u16* __restrict__ xb, int* __restrict__ cnt,
    int* __restrict__ tok, float* __restrict__ wgt)
{
  __shared__ int lcnt[NEXP];
  __shared__ int lbase[NEXP];
  __shared__ int rec_i[32];
  __shared__ int rec_p1[32], rec_p2[32];
  __shared__ float rec_w1[32], rec_w2[32];

  int tid = threadIdx.x, wave = tid >> 6, lane = tid & 63;
  if (tid < NEXP) lcnt[tid] = 0;
  __syncthreads();

  int tbase = blockIdx.x * 32 + wave * 8;
#pragma unroll
  for (int it = 0; it < 8; ++it) {
    int n = tbase + it;
    const float4* xr = (const float4*)(x + (size_t)n * CDIM) + lane * 4;
    float4 xv[4];
#pragma unroll
    for (int j = 0; j < 4; j++) xv[j] = xr[j];
    u16x8 rA, rB;
    rA[0]=f2bf(xv[0].x); rA[1]=f2bf(xv[0].y); rA[2]=f2bf(xv[0].z); rA[3]=f2bf(xv[0].w);
    rA[4]=f2bf(xv[1].x); rA[5]=f2bf(xv[1].y); rA[6]=f2bf(xv[1].z); rA[7]=f2bf(xv[1].w);
    rB[0]=f2bf(xv[2].x); rB[1]=f2bf(xv[2].y); rB[2]=f2bf(xv[2].z); rB[3]=f2bf(xv[2].w);
    rB[4]=f2bf(xv[3].x); rB[5]=f2bf(xv[3].y); rB[6]=f2bf(xv[3].z); rB[7]=f2bf(xv[3].w);
    u16* xrow = xb + (size_t)n * CDIM + lane * 16;
    *(u16x8*)xrow = rA;
    *(u16x8*)(xrow + 8) = rB;

    float s[NEXP];
#pragma unroll
    for (int e = 0; e < NEXP; e++) {
      const float4* g = (const float4*)(gw + (size_t)e * CDIM) + lane * 4;
      float a = 0.f;
#pragma unroll
      for (int j = 0; j < 4; j++) {
        float4 gv = g[j];
        a += xv[j].x * gv.x + xv[j].y * gv.y + xv[j].z * gv.z + xv[j].w * gv.w;
      }
#pragma unroll
      for (int o = 32; o > 0; o >>= 1) a += __shfl_xor(a, o);
      s[e] = a;
    }
    if (lane == 0) {
      float m = s[0];
      for (int e = 1; e < NEXP; e++) m = fmaxf(m, s[e]);
      float p[NEXP], sum = 0.f;
      for (int e = 0; e < NEXP; e++) { p[e] = __expf(s[e] - m); sum += p[e]; }
      int i1 = 0;
      for (int e = 1; e < NEXP; e++) if (p[e] > p[i1]) i1 = e;
      int i2 = (i1 == 0) ? 1 : 0;
      for (int e = 0; e < NEXP; e++) if (e != i1 && p[e] > p[i2]) i2 = e;
      float w1 = p[i1] / sum, w2 = p[i2] / sum;
#pragma unroll
      for (int e = 0; e < NEXP; e++) scores[(size_t)n * NEXP + e] = s[e];
      int p1 = atomicAdd(&lcnt[i1], 1);
      int p2 = atomicAdd(&lcnt[i2], 1);
      int slot = wave * 8 + it;
      rec_i[slot] = i1 | (i2 << 8);
      rec_p1[slot] = p1; rec_p2[slot] = p2;
      rec_w1[slot] = w1; rec_w2[slot] = w2;
    }
  }
  __syncthreads();
  if (tid < NEXP) lbase[tid] = atomicAdd(&cnt[tid], lcnt[tid]);
  __syncthreads();
  if (tid < 32) {
    int n = blockIdx.x * 32 + tid;
    int i1 = rec_i[tid] & 0xff, i2 = rec_i[tid] >> 8;
    int q1 = lbase[i1] + rec_p1[tid];
    int q2 = lbase[i2] + rec_p2[tid];
    tok[i1 * NTOK + q1] = n; wgt[i1 * NTOK + q1] = rec_w1[tid];
    tok[i2 * NTOK + q2] = n; wgt[i2 * NTOK + q2] = rec_w2[tid];
  }
}

__global__ void prefix_kernel(const int* __restrict__ cnt, int* __restrict__ prefix) {
  if (threadIdx.x == 0 && blockIdx.x == 0) {
    int a = 0;
    for (int e = 0; e < NEXP; e++) { prefix[e] = a; a += cnt[e]; }
    prefix[NEXP] = a;
  }
}

// ---------------- tiled transpose f32[R][C] -> bf16[C][R], batched in z ------
__global__ __launch_bounds__(256) void transpose_kernel(const float* __restrict__ src,
    u16* __restrict__ dst, int R, int C)
{
  __shared__ float tile[32][33];
  size_t base = (size_t)blockIdx.z * R * C;
  int c0 = blockIdx.x * 32, r0 = blockIdx.y * 32;
  int tx = threadIdx.x & 31, ty = threadIdx.x >> 5;
#pragma unroll
  for (int i = 0; i < 4; i++) {
    int r = ty + i * 8;
    tile[r][tx] = src[base + (size_t)(r0 + r) * C + c0 + tx];
  }
  __syncthreads();
#pragma unroll
  for (int i = 0; i < 4; i++) {
    int c = ty + i * 8;
    dst[base + (size_t)(c0 + c) * R + r0 + tx] = f2bf(tile[tx][c]);
  }
}

// -------- interleaving transpose: dst[2j]=s1 col j, dst[2j+1]=s2 col j ------
__global__ __launch_bounds__(256) void transpose_i_kernel(
    const float* __restrict__ s1, const float* __restrict__ s2,
    u16* __restrict__ dst, int R, int C, size_t sstride, size_t dstride)
{
  __shared__ float t1[32][33], t2[32][33];
  size_t sbase = (size_t)blockIdx.z * sstride;
  size_t dbase = (size_t)blockIdx.z * dstride;
  int c0 = blockIdx.x * 32, r0 = blockIdx.y * 32;
  int tx = threadIdx.x & 31, ty = threadIdx.x >> 5;
#pragma unroll
  for (int i = 0; i < 4; i++) {
    int r = ty + i * 8;
    t1[r][tx] = s1[sbase + (size_t)(r0 + r) * C + c0 + tx];
    t2[r][tx] = s2[sbase + (size_t)(r0 + r) * C + c0 + tx];
  }
  __syncthreads();
#pragma unroll
  for (int i = 0; i < 4; i++) {
    int c = ty + i * 8;
    dst[dbase + (size_t)(2 * (c0 + c) + 0) * R + r0 + tx] = f2bf(t1[tx][c]);
    dst[dbase + (size_t)(2 * (c0 + c) + 1) * R + r0 + tx] = f2bf(t2[tx][c]);
  }
}

// ====== 256-row tile GEMM, BK=64, 8 waves, counted-vmcnt 4-phase pipeline ====
// Chunk = 64 rows x 64 cols (1 GLD16/thread). Stage tile t+1 DURING tile t in
// CONSUMPTION order, 2 chunks/phase:
//   BN=256: P0:B0B1  P1:B2B3  P2:A0A2  P3:A1A3
//   BN=128: P0:B0B1  P1:A0A2  P2:A1A3  P3:--
// Consumption: P0 needs {B*,A0,A2}, P1 needs {A1,A3}; P2/P3 reuse landed
// chunks (slot1). Waits: vmcnt(2) at P0-end (A1,A3 of t: exactly 2 younger
// loads outstanding) and P3-end (next tile's P0 set: 2 younger = its A1,A3).
// NEVER vmcnt(0) in steady state (m218 lever). Last tile peels to vmcnt(0).
// Swizzle (validated: 0 bank conflicts): linear gload dest; SOURCE col-chunk
// XOR row&7; ds_read slot XORed identically.
// EPI: 0 SwiGLU pair epilogue (W1/W2 interleaved cols; shfl_xor(1)).
//      2 store f32.  4 *wgt + atomicAdd scatter to out rows tok[].
// AMODE: 0 direct; 1 gather via tok (H compacted); 2 compacted A, scatter.
#define BM2 256
#define BK2 64

template<int EPI, int AMODE, int BN_>
__global__ __launch_bounds__(512, 2) void gemm256(
    const u16* __restrict__ A, int lda,
    const u16* __restrict__ B, size_t bstride, int ldb,
    int M, int K,
    u16* __restrict__ Hout, int ldh,
    float* __restrict__ outF, int ldo,
    const int* __restrict__ cnt, const int* __restrict__ prefix,
    const int* __restrict__ tok, const float* __restrict__ wgt)
{
  constexpr int WN = BN_ / 4;        // per-wave col span
  constexpr int N_REP = WN / 16;     // 16-col frags per wave
  constexpr int ACH = 4;             // A stage chunks (64 rows each)
  constexpr int BCH = BN_ / 64;      // B stage chunks

  int e = blockIdx.z;
  int Mloc = (AMODE == 0) ? M : cnt[e];
  int mbase = blockIdx.y * BM2;
  if (AMODE != 0 && mbase >= Mloc) return;
  int nbase = blockIdx.x * BN_;
  int tid = threadIdx.x;
  int lane = tid & 63;
  int wid = tid >> 6;
  int wr = wid >> 2, wc = wid & 3;   // 2 x 4 wave grid
  int fr = lane & 15;

  __shared__ __align__(16) u16 As[2][BM2 * BK2];
  __shared__ __align__(16) u16 Bs[2][BN_ * BK2];

  // ---- staging addressing (linear LDS dest = base + tid*16B) ----
  int srow = tid >> 3;                         // 0..63: row within chunk
  int scol = ((tid & 7) ^ (srow & 7)) * 8;     // inverse-swizzled source col
  int pfx = (AMODE == 0) ? 0 : prefix[e];

  size_t arow[ACH];
#pragma unroll
  for (int c = 0; c < ACH; c++) {
    int rloc = mbase + c * 64 + srow;
    if (AMODE == 0)      arow[c] = rloc;
    else if (AMODE == 1) arow[c] = tok[e * NTOK + min(rloc, Mloc - 1)];
    else                 arow[c] = pfx + min(rloc, Mloc - 1);
  }
  const u16* Aps[ACH];
#pragma unroll
  for (int c = 0; c < ACH; c++) Aps[c] = A + arow[c] * (size_t)lda + scol;
  const u16* Bb = B + ((AMODE != 0) ? (size_t)e * bstride : 0);
  const u16* Bps[BCH];
#pragma unroll
  for (int c = 0; c < BCH; c++)
    Bps[c] = Bb + (size_t)(nbase + c * 64 + srow) * ldb + scol;

  auto SA = [&](int buf, int ch, int kof) {
    GLD16(Aps[ch] + kof, &As[buf][ch * 4096 + tid * 8]);
  };
  auto SB = [&](int buf, int ch, int kof) {
    GLD16(Bps[ch] + kof, &Bs[buf][ch * 4096 + tid * 8]);
  };

  f32x4 acc[8][N_REP] = {};

  int nt = K / BK2;
  // ---- prologue: tile 0, consumption order; A1,A3 issued LAST ----
#pragma unroll
  for (int cb = 0; cb < BCH; cb++) SB(0, cb, 0);
  SA(0, 0, 0); SA(0, 2, 0); SA(0, 1, 0); SA(0, 3, 0);
  asm volatile("s_waitcnt vmcnt(2)" ::: "memory");   // all but A1,A3 landed
  __builtin_amdgcn_s_barrier();
  __builtin_amdgcn_sched_barrier(0);

  int slot0 = (((lane >> 4)) ^ (fr & 7)) << 3;        // ks=0 swizzled chunk
  int slot1 = ((4 + (lane >> 4)) ^ (fr & 7)) << 3;    // ks=1 swizzled chunk

  for (int t = 0; t < nt; ++t) {
    int c = t & 1, o = c ^ 1;
    bool pf = (t + 1 < nt);
    int kof = (t + 1) * BK2;
    const u16* asb = &As[c][(wr * 128 + fr) * BK2];
    const u16* bsb = &Bs[c][(wc * WN + fr) * BK2];

    // ---- P0: read b0+a0 (slot0); stage B0,B1(t+1) ----
    bf16x8 b0[N_REP], a0[4];
#pragma unroll
    for (int n = 0; n < N_REP; n++) b0[n] = *(const bf16x8*)&bsb[n * 1024 + slot0];
#pragma unroll
    for (int m = 0; m < 4; m++) a0[m] = *(const bf16x8*)&asb[m * 1024 + slot0];
    if (pf) { SB(o, 0, kof); SB(o, 1, kof); }
    __builtin_amdgcn_s_barrier();
    asm volatile("s_waitcnt lgkmcnt(0)" ::: "memory");
    __builtin_amdgcn_sched_barrier(0);
    __builtin_amdgcn_s_setprio(1);
#pragma unroll
    for (int m = 0; m < 4; m++)
#pragma unroll
      for (int n = 0; n < N_REP; n++)
        acc[m][n] = __builtin_amdgcn_mfma_f32_16x16x32_bf16(a0[m], b0[n], acc[m][n], 0, 0, 0);
    __builtin_amdgcn_s_setprio(0);
    if (pf) asm volatile("s_waitcnt vmcnt(2)" ::: "memory");  // A1,A3(t) landed
    else    asm volatile("s_waitcnt vmcnt(0)" ::: "memory");
    __builtin_amdgcn_s_barrier();
    __builtin_amdgcn_sched_barrier(0);

    // ---- P1: read a1 (slot0); stage B2,B3 / A0,A2 (t+1) ----
    bf16x8 a1[4];
#pragma unroll
    for (int m = 0; m < 4; m++) a1[m] = *(const bf16x8*)&asb[(4 + m) * 1024 + slot0];
    if (pf) {
      if constexpr (BCH == 4) { SB(o, 2, kof); SB(o, 3, kof); }
      else                    { SA(o, 0, kof); SA(o, 2, kof); }
    }
    __builtin_amdgcn_s_barrier();
    asm volatile("s_waitcnt lgkmcnt(0)" ::: "memory");
    __builtin_amdgcn_sched_barrier(0);
    __builtin_amdgcn_s_setprio(1);
#pragma unroll
    for (int m = 0; m < 4; m++)
#pragma unroll
      for (int n = 0; n < N_REP; n++)
        acc[4 + m][n] = __builtin_amdgcn_mfma_f32_16x16x32_bf16(a1[m], b0[n], acc[4 + m][n], 0, 0, 0);
    __builtin_amdgcn_s_setprio(0);
    __builtin_amdgcn_s_barrier();
    __builtin_amdgcn_sched_barrier(0);

    // ---- P2: read b1+a2 (slot1); stage A0,A2 / A1,A3 (t+1) ----
    bf16x8 b1[N_REP], a2[4];
#pragma unroll
    for (int n = 0; n < N_REP; n++) b1[n] = *(const bf16x8*)&bsb[n * 1024 + slot1];
#pragma unroll
    for (int m = 0; m < 4; m++) a2[m] = *(const bf16x8*)&asb[(4 + m) * 1024 + slot1];
    if (pf) {
      if constexpr (BCH == 4) { SA(o, 0, kof); SA(o, 2, kof); }
      else                    { SA(o, 1, kof); SA(o, 3, kof); }
    }
    __builtin_amdgcn_s_barrier();
    asm volatile("s_waitcnt lgkmcnt(0)" ::: "memory");
    __builtin_amdgcn_sched_barrier(0);
    __builtin_amdgcn_s_setprio(1);
#pragma unroll
    for (int m = 0; m < 4; m++)
#pragma unroll
      for (int n = 0; n < N_REP; n++)
        acc[4 + m][n] = __builtin_amdgcn_mfma_f32_16x16x32_bf16(a2[m], b1[n], acc[4 + m][n], 0, 0, 0);
    __builtin_amdgcn_s_setprio(0);
    __builtin_amdgcn_s_barrier();
    __builtin_amdgcn_sched_barrier(0);

    // ---- P3: read a3 (slot1); stage A1,A3 (t+1, BN=256 only) ----
    bf16x8 a3[4];
#pragma unroll
    for (int m = 0; m < 4; m++) a3[m] = *(const bf16x8*)&asb[m * 1024 + slot1];
    if (pf) {
      if constexpr (BCH == 4) { SA(o, 1, kof); SA(o, 3, kof); }
    }
    __builtin_amdgcn_s_barrier();
    asm volatile("s_waitcnt lgkmcnt(0)" ::: "memory");
    __builtin_amdgcn_sched_barrier(0);
    __builtin_amdgcn_s_setprio(1);
#pragma unroll
    for (int m = 0; m < 4; m++)
#pragma unroll
      for (int n = 0; n < N_REP; n++)
        acc[m][n] = __builtin_amdgcn_mfma_f32_16x16x32_bf16(a3[m], b1[n], acc[m][n], 0, 0, 0);
    __builtin_amdgcn_s_setprio(0);
    if (pf) asm volatile("s_waitcnt vmcnt(2)" ::: "memory");  // (t+1) P0-set landed
    __builtin_amdgcn_s_barrier();
    __builtin_amdgcn_sched_barrier(0);
  }

  // ---- epilogue — C/D layout: col = lane&15, row = (lane>>4)*4 + j ----
#pragma unroll
  for (int m = 0; m < 8; m++) {
#pragma unroll
    for (int j = 0; j < 4; j++) {
      int rloc = wr * 128 + m * 16 + (lane >> 4) * 4 + j;
      int rr = mbase + rloc;
      if (AMODE != 0 && rr >= Mloc) continue;
      int tk = 0; float wv = 0.f;
      if (EPI == 4) { tk = tok[e * NTOK + rr]; wv = wgt[e * NTOK + rr]; }
#pragma unroll
      for (int n = 0; n < N_REP; n++) {
        int wcol = wc * WN + n * 16 + fr;
        float v = acc[m][n][j];
        if (EPI == 0) {
          float o = __shfl_xor(v, 1);        // partner holds the other of (g,v)
          float g  = (fr & 1) ? o : v;
          float vv = (fr & 1) ? v : o;
          float hv = (g / (1.f + __expf(-g))) * vv;
          if (!(fr & 1))
            Hout[(size_t)(pfx + rr) * ldh + ((nbase + wcol) >> 1)] = f2bf(hv);
        } else if (EPI == 2) {
          outF[(size_t)rr * ldo + nbase + wcol] = v;
        } else {
          unsafeAtomicAdd(&outF[(size_t)tk * ldo + nbase + wcol], v * wv);
        }
      }
    }
  }
}

// ---------------- host ----------------
extern "C" void kernel_launch(void* const* d_in, const int* in_sizes, int n_in,
                              void* d_out, int out_size, void* d_ws, size_t ws_size,
                              hipStream_t stream)
{
  const float* x   = (const float*)d_in[0];
  const float* gw  = (const float*)d_in[1];
  const float* ew1 = (const float*)d_in[2];
  const float* ew2 = (const float*)d_in[3];
  const float* ewp = (const float*)d_in[4];
  const float* sw1 = (const float*)d_in[5];
  const float* sw2 = (const float*)d_in[6];
  const float* swp = (const float*)d_in[7];
  float* out    = (float*)d_out;
  float* scores = out + (size_t)NTOK * CDIM;

  char* wsp = (char*)d_ws;
  size_t off = 0;
  auto alloc = [&](size_t bytes) -> void* {
    void* p = wsp + off; off += (bytes + 255) & ~(size_t)255; return p;
  };
  u16* xb   = (u16*)alloc((size_t)NTOK * CDIM * 2);
  u16* swi  = (u16*)alloc((size_t)2 * FSDIM * CDIM * 2);          // interleaved shared W1/W2
  u16* ewi  = (u16*)alloc((size_t)NEXP * 2 * FEDIM * CDIM * 2);   // interleaved expert W1/W2
  u16* swpt = (u16*)alloc((size_t)CDIM * FSDIM * 2);
  u16* ewpt = (u16*)alloc((size_t)NEXP * CDIM * FEDIM * 2);
  u16* hs   = (u16*)alloc((size_t)NTOK * FSDIM * 2);              // shared h
  u16* he   = (u16*)alloc((size_t)2 * NTOK * FEDIM * 2);          // expert h (compacted)
  int* cnt  = (int*)alloc(256);
  int* pfx  = (int*)alloc(256);
  int* tok  = (int*)alloc((size_t)NEXP * NTOK * 4);
  float* wgt = (float*)alloc((size_t)NEXP * NTOK * 4);
  if (off > ws_size) return;

  hipMemsetAsync(cnt, 0, 32, stream);
  gate_kernel<<<NTOK / 32, 256, 0, stream>>>(x, gw, scores, xb, cnt, tok, wgt);
  prefix_kernel<<<1, 64, 0, stream>>>(cnt, pfx);
  transpose_i_kernel<<<dim3(FSDIM/32, CDIM/32, 1), 256, 0, stream>>>(
      sw1, sw2, swi, CDIM, FSDIM, 0, 0);
  transpose_i_kernel<<<dim3(FEDIM/32, CDIM/32, NEXP), 256, 0, stream>>>(
      ew1, ew2, ewi, CDIM, FEDIM, (size_t)CDIM * FEDIM, (size_t)2 * FEDIM * CDIM);
  transpose_kernel<<<dim3(CDIM/32, FSDIM/32, 1), 256, 0, stream>>>(swp, swpt, FSDIM, CDIM);
  transpose_kernel<<<dim3(CDIM/32, FEDIM/32, NEXP), 256, 0, stream>>>(ewp, ewpt, FEDIM, CDIM);

  // shared FFN: fused SwiGLU (N_eff = 2*FS = 8192, K=1024) -> hs [8192][4096]
  gemm256<0,0,256><<<dim3(2*FSDIM/256, NTOK/256, 1), 512, 0, stream>>>(
      xb, CDIM, swi, 0, CDIM, NTOK, CDIM, hs, FSDIM, nullptr, 0,
      nullptr, nullptr, nullptr, nullptr);
  // shared proj: [8192][4096] @ [4096][1024] -> out (f32 store)
  gemm256<2,0,128><<<dim3(CDIM/128, NTOK/256, 1), 512, 0, stream>>>(
      hs, FSDIM, swpt, 0, FSDIM, NTOK, FSDIM, nullptr, 0, out, CDIM,
      nullptr, nullptr, nullptr, nullptr);

  // experts: fused SwiGLU on gathered rows (N_eff = 2*FE = 2048) -> he compacted
  gemm256<0,1,256><<<dim3(2*FEDIM/256, NTOK/256, NEXP), 512, 0, stream>>>(
      xb, CDIM, ewi, (size_t)2 * FEDIM * CDIM, CDIM, 0, CDIM, he, FEDIM, nullptr, 0,
      cnt, pfx, tok, nullptr);
  // expert proj: weighted atomic scatter into out
  gemm256<4,2,128><<<dim3(CDIM/128, NTOK/256, NEXP), 512, 0, stream>>>(
      he, FEDIM, ewpt, (size_t)CDIM * FEDIM, FEDIM, 0, FEDIM, nullptr, 0, out, CDIM,
      cnt, pfx, tok, wgt);
}

// Round 8
// 565.098 us; speedup vs baseline: 1.0899x; 1.0899x over previous
//
#include <hip/hip_runtime.h>

typedef unsigned short u16;
typedef unsigned int u32;
typedef __bf16 bf16x8 __attribute__((ext_vector_type(8)));
typedef float f32x4 __attribute__((ext_vector_type(4)));
typedef u16 u16x8 __attribute__((ext_vector_type(8)));

#define NTOK 8192
#define CDIM 1024
#define NEXP 8
#define FEDIM 1024
#define FSDIM 4096

#define GLD16(gp, lp) __builtin_amdgcn_global_load_lds( \
    (const __attribute__((address_space(1))) void*)(gp), \
    (__attribute__((address_space(3))) void*)(lp), 16, 0, 0)

__device__ __forceinline__ u16 f2bf(float f) {
  u32 u = __float_as_uint(f);
  u += 0x7FFFu + ((u >> 16) & 1u);   // RNE
  return (u16)(u >> 16);
}
__device__ __forceinline__ float bf2f(u16 h) {
  return __uint_as_float(((u32)h) << 16);
}

// ---------------- gate: scores, softmax, top-2, expert lists, x->bf16 -------
__global__ __launch_bounds__(256) void gate_kernel(
    const float* __restrict__ x, const float* __restrict__ gw,
    float* __restrict__ scores, u16* __restrict__ xb, int* __restrict__ cnt,
    int* __restrict__ tok, float* __restrict__ wgt)
{
  __shared__ int lcnt[NEXP];
  __shared__ int lbase[NEXP];
  __shared__ int rec_i[32];
  __shared__ int rec_p1[32], rec_p2[32];
  __shared__ float rec_w1[32], rec_w2[32];

  int tid = threadIdx.x, wave = tid >> 6, lane = tid & 63;
  if (tid < NEXP) lcnt[tid] = 0;
  __syncthreads();

  int tbase = blockIdx.x * 32 + wave * 8;
#pragma unroll
  for (int it = 0; it < 8; ++it) {
    int n = tbase + it;
    const float4* xr = (const float4*)(x + (size_t)n * CDIM) + lane * 4;
    float4 xv[4];
#pragma unroll
    for (int j = 0; j < 4; j++) xv[j] = xr[j];
    u16x8 rA, rB;
    rA[0]=f2bf(xv[0].x); rA[1]=f2bf(xv[0].y); rA[2]=f2bf(xv[0].z); rA[3]=f2bf(xv[0].w);
    rA[4]=f2bf(xv[1].x); rA[5]=f2bf(xv[1].y); rA[6]=f2bf(xv[1].z); rA[7]=f2bf(xv[1].w);
    rB[0]=f2bf(xv[2].x); rB[1]=f2bf(xv[2].y); rB[2]=f2bf(xv[2].z); rB[3]=f2bf(xv[2].w);
    rB[4]=f2bf(xv[3].x); rB[5]=f2bf(xv[3].y); rB[6]=f2bf(xv[3].z); rB[7]=f2bf(xv[3].w);
    u16* xrow = xb + (size_t)n * CDIM + lane * 16;
    *(u16x8*)xrow = rA;
    *(u16x8*)(xrow + 8) = rB;

    float s[NEXP];
#pragma unroll
    for (int e = 0; e < NEXP; e++) {
      const float4* g = (const float4*)(gw + (size_t)e * CDIM) + lane * 4;
      float a = 0.f;
#pragma unroll
      for (int j = 0; j < 4; j++) {
        float4 gv = g[j];
        a += xv[j].x * gv.x + xv[j].y * gv.y + xv[j].z * gv.z + xv[j].w * gv.w;
      }
#pragma unroll
      for (int o = 32; o > 0; o >>= 1) a += __shfl_xor(a, o);
      s[e] = a;
    }
    if (lane == 0) {
      float m = s[0];
      for (int e = 1; e < NEXP; e++) m = fmaxf(m, s[e]);
      float p[NEXP], sum = 0.f;
      for (int e = 0; e < NEXP; e++) { p[e] = __expf(s[e] - m); sum += p[e]; }
      int i1 = 0;
      for (int e = 1; e < NEXP; e++) if (p[e] > p[i1]) i1 = e;
      int i2 = (i1 == 0) ? 1 : 0;
      for (int e = 0; e < NEXP; e++) if (e != i1 && p[e] > p[i2]) i2 = e;
      float w1 = p[i1] / sum, w2 = p[i2] / sum;
#pragma unroll
      for (int e = 0; e < NEXP; e++) scores[(size_t)n * NEXP + e] = s[e];
      int p1 = atomicAdd(&lcnt[i1], 1);
      int p2 = atomicAdd(&lcnt[i2], 1);
      int slot = wave * 8 + it;
      rec_i[slot] = i1 | (i2 << 8);
      rec_p1[slot] = p1; rec_p2[slot] = p2;
      rec_w1[slot] = w1; rec_w2[slot] = w2;
    }
  }
  __syncthreads();
  if (tid < NEXP) lbase[tid] = atomicAdd(&cnt[tid], lcnt[tid]);
  __syncthreads();
  if (tid < 32) {
    int n = blockIdx.x * 32 + tid;
    int i1 = rec_i[tid] & 0xff, i2 = rec_i[tid] >> 8;
    int q1 = lbase[i1] + rec_p1[tid];
    int q2 = lbase[i2] + rec_p2[tid];
    tok[i1 * NTOK + q1] = n; wgt[i1 * NTOK + q1] = rec_w1[tid];
    tok[i2 * NTOK + q2] = n; wgt[i2 * NTOK + q2] = rec_w2[tid];
  }
}

// -------- batched 64x32 transpose f32[R][C] -> bf16[C][R], wide stores ------
// z selects source: si = z / nz_per_src in {s0,s1,s2}; src batch = z % nz;
// dst batches contiguous at dst + z*R*C. Loads 128B coalesced; stores short2
// (128B per 32 lanes, vs 64B in the old 32x32 kernel).
__global__ __launch_bounds__(256) void transpose64_kernel(
    const float* __restrict__ s0, const float* __restrict__ s1,
    const float* __restrict__ s2, u16* __restrict__ dst,
    int R, int C, int nz_per_src)
{
  __shared__ float tile[64][33];
  int z = blockIdx.z;
  int si = z / nz_per_src;
  const float* src = (si == 0) ? s0 : ((si == 1) ? s1 : s2);
  size_t sbase = (size_t)(z % nz_per_src) * R * C;
  size_t dbase = (size_t)z * R * C;
  int c0 = blockIdx.x * 32, r0 = blockIdx.y * 64;
  int tx = threadIdx.x & 31, ty = threadIdx.x >> 5;   // ty 0..7
#pragma unroll
  for (int p = 0; p < 8; p++) {
    int r = ty + p * 8;
    tile[r][tx] = src[sbase + (size_t)(r0 + r) * C + c0 + tx];
  }
  __syncthreads();
#pragma unroll
  for (int p = 0; p < 4; p++) {
    int cc = ty + p * 8;
    u32 v = (u32)f2bf(tile[2 * tx][cc]) | ((u32)f2bf(tile[2 * tx + 1][cc]) << 16);
    *(u32*)&dst[dbase + (size_t)(c0 + cc) * R + r0 + 2 * tx] = v;
  }
}

#define BM 128
#define BN 128
#define BK 32
#define TILE (BM * BK)   // 4096 u16 = 8 KB

// ---------------- fused SwiGLU GEMM: H = silu(A@B1^T) * (A@B2^T) -------------
// Round-4 structure verbatim (808 TF measured): double-buffered LDS, 2-phase,
// __launch_bounds__(256,2). Prefix computed in-kernel (8-elem scan of cnt).
// AMODE 0: direct rows; 1: rows gathered via tok list, H written compacted.
template<int AMODE>
__global__ __launch_bounds__(256, 2) void gemm_swiglu(
    const u16* __restrict__ A, int lda,
    const u16* __restrict__ B1, const u16* __restrict__ B2,
    size_t bstride, int ldb,
    int M, int K,
    u16* __restrict__ H, int ldh,
    const int* __restrict__ cnt, const int* __restrict__ tok)
{
  int e = blockIdx.z;
  int Mloc = (AMODE == 0) ? M : cnt[e];
  int mbase = blockIdx.y * BM;
  if (AMODE != 0 && mbase >= Mloc) return;
  int nbase = blockIdx.x * BN;
  int tid = threadIdx.x, wid = tid >> 6, lane = tid & 63;

  __shared__ __align__(16) u16 As[2][TILE];
  __shared__ __align__(16) u16 Bs1[2][TILE];
  __shared__ __align__(16) u16 Bs2[2][TILE];

  int sr = lane >> 2;             // 0..15 row within 16-row staging group
  int kg = (lane & 3) * 8;        // 8 bf16 = 16B per lane
  int arow0 = wid * 32 + sr;
  int arow1 = arow0 + 16;

  int pfx = 0;
  if (AMODE != 0) for (int i = 0; i < NEXP; i++) pfx += (i < e) ? cnt[i] : 0;

  size_t r0, r1;
  if (AMODE == 0) {
    r0 = mbase + arow0; r1 = mbase + arow1;
  } else {
    r0 = tok[e * NTOK + min(mbase + arow0, Mloc - 1)];
    r1 = tok[e * NTOK + min(mbase + arow1, Mloc - 1)];
  }
  const u16* Ap0 = A + r0 * (size_t)lda + kg;
  const u16* Ap1 = A + r1 * (size_t)lda + kg;
  size_t boff = (AMODE != 0) ? (size_t)e * bstride : 0;
  const u16* B1p0 = B1 + boff + (size_t)(nbase + arow0) * ldb + kg;
  const u16* B1p1 = B1 + boff + (size_t)(nbase + arow1) * ldb + kg;
  const u16* B2p0 = B2 + boff + (size_t)(nbase + arow0) * ldb + kg;
  const u16* B2p1 = B2 + boff + (size_t)(nbase + arow1) * ldb + kg;

  int ldsw0 = (wid * 32) * BK;        // wave slice, rows [w*32, w*32+16)
  int ldsw1 = (wid * 32 + 16) * BK;   // rows [w*32+16, w*32+32)

  int wr = wid >> 1, wc = wid & 1;
  int fr = lane & 15, fgk = (lane >> 4) * 8;

  f32x4 acc1[4][4] = {};
  f32x4 acc2[4][4] = {};

  int nt = K / BK;
  // prologue: stage tile 0 into buffer 0
  GLD16(Ap0,  &As [0][ldsw0]); GLD16(Ap1,  &As [0][ldsw1]);
  GLD16(B1p0, &Bs1[0][ldsw0]); GLD16(B1p1, &Bs1[0][ldsw1]);
  GLD16(B2p0, &Bs2[0][ldsw0]); GLD16(B2p1, &Bs2[0][ldsw1]);
  Ap0 += BK; Ap1 += BK; B1p0 += BK; B1p1 += BK; B2p0 += BK; B2p1 += BK;
  __syncthreads();

  int cur = 0;
  for (int t = 0; t < nt; ++t) {
    int nxt = cur ^ 1;
    if (t + 1 < nt) {   // prefetch next tile into the idle buffer
      GLD16(Ap0,  &As [nxt][ldsw0]); GLD16(Ap1,  &As [nxt][ldsw1]);
      GLD16(B1p0, &Bs1[nxt][ldsw0]); GLD16(B1p1, &Bs1[nxt][ldsw1]);
      GLD16(B2p0, &Bs2[nxt][ldsw0]); GLD16(B2p1, &Bs2[nxt][ldsw1]);
      Ap0 += BK; Ap1 += BK; B1p0 += BK; B1p1 += BK; B2p0 += BK; B2p1 += BK;
    }
    const u16* as = As[cur];
    const u16* b1s = Bs1[cur];
    const u16* b2s = Bs2[cur];
    bf16x8 af[4], b1f[4], b2f[4];
#pragma unroll
    for (int m = 0; m < 4; m++)
      af[m] = *(const bf16x8*)&as[(wr * 64 + m * 16 + fr) * BK + fgk];
#pragma unroll
    for (int n = 0; n < 4; n++) {
      b1f[n] = *(const bf16x8*)&b1s[(wc * 64 + n * 16 + fr) * BK + fgk];
      b2f[n] = *(const bf16x8*)&b2s[(wc * 64 + n * 16 + fr) * BK + fgk];
    }
#pragma unroll
    for (int m = 0; m < 4; m++)
#pragma unroll
      for (int n = 0; n < 4; n++) {
        acc1[m][n] = __builtin_amdgcn_mfma_f32_16x16x32_bf16(af[m], b1f[n], acc1[m][n], 0, 0, 0);
        acc2[m][n] = __builtin_amdgcn_mfma_f32_16x16x32_bf16(af[m], b2f[n], acc2[m][n], 0, 0, 0);
      }
    __syncthreads();   // drains prefetch vmcnt + all lgkm; flip buffers
    cur = nxt;
  }

  // epilogue — C/D layout: col = lane&15, row = (lane>>4)*4 + j
  int fg4 = (lane >> 4) * 4;
#pragma unroll
  for (int m = 0; m < 4; m++) {
#pragma unroll
    for (int j = 0; j < 4; j++) {
      int rloc = wr * 64 + m * 16 + fg4 + j;
      int rr = mbase + rloc;
      if (AMODE != 0 && rr >= Mloc) continue;
      size_t orow = (size_t)(pfx + rr);
#pragma unroll
      for (int n = 0; n < 4; n++) {
        int col = nbase + wc * 64 + n * 16 + fr;
        float g = acc1[m][n][j];
        float v = acc2[m][n][j];
        float hv = (g / (1.f + __expf(-g))) * v;   // silu(g)*v
        H[orow * (size_t)ldh + col] = f2bf(hv);
      }
    }
  }
}

// ---------------- proj GEMM, double-buffered (round-4 structure) ------------
// EPI: 2 store f32, 4 scale-by-weight + atomicAdd scatter to out rows tok[].
// AMODE: 0 direct rows, 2 rows at prefix[e]+r (compacted expert h).
template<int EPI, int AMODE>
__global__ __launch_bounds__(256, 2) void gemm_proj(
    const u16* __restrict__ A, int lda,
    const u16* __restrict__ B, size_t bstride, int ldb,
    int M, int K,
    float* __restrict__ outF, int ldo,
    const int* __restrict__ cnt, const int* __restrict__ tok,
    const float* __restrict__ wgt)
{
  int e = blockIdx.z;
  int Mloc = (AMODE == 0) ? M : cnt[e];
  int mbase = blockIdx.y * BM;
  if (AMODE != 0 && mbase >= Mloc) return;
  int nbase = blockIdx.x * BN;
  int tid = threadIdx.x, wid = tid >> 6, lane = tid & 63;

  __shared__ __align__(16) u16 As[2][TILE];
  __shared__ __align__(16) u16 Bs[2][TILE];

  int sr = lane >> 2;
  int kg = (lane & 3) * 8;
  int arow0 = wid * 32 + sr;
  int arow1 = arow0 + 16;

  int pfx = 0;
  if (AMODE != 0) for (int i = 0; i < NEXP; i++) pfx += (i < e) ? cnt[i] : 0;

  size_t r0, r1;
  if (AMODE == 0) {
    r0 = mbase + arow0; r1 = mbase + arow1;
  } else {
    r0 = pfx + min(mbase + arow0, Mloc - 1);
    r1 = pfx + min(mbase + arow1, Mloc - 1);
  }
  const u16* Ap0 = A + r0 * (size_t)lda + kg;
  const u16* Ap1 = A + r1 * (size_t)lda + kg;
  const u16* Bb = B + ((AMODE != 0) ? (size_t)e * bstride : 0);
  const u16* Bp0 = Bb + (size_t)(nbase + arow0) * ldb + kg;
  const u16* Bp1 = Bb + (size_t)(nbase + arow1) * ldb + kg;

  int ldsw0 = (wid * 32) * BK;
  int ldsw1 = (wid * 32 + 16) * BK;

  int wr = wid >> 1, wc = wid & 1;
  int fr = lane & 15, fgk = (lane >> 4) * 8;

  f32x4 acc[4][4] = {};

  int nt = K / BK;
  GLD16(Ap0, &As[0][ldsw0]); GLD16(Ap1, &As[0][ldsw1]);
  GLD16(Bp0, &Bs[0][ldsw0]); GLD16(Bp1, &Bs[0][ldsw1]);
  Ap0 += BK; Ap1 += BK; Bp0 += BK; Bp1 += BK;
  __syncthreads();

  int cur = 0;
  for (int t = 0; t < nt; ++t) {
    int nxt = cur ^ 1;
    if (t + 1 < nt) {
      GLD16(Ap0, &As[nxt][ldsw0]); GLD16(Ap1, &As[nxt][ldsw1]);
      GLD16(Bp0, &Bs[nxt][ldsw0]); GLD16(Bp1, &Bs[nxt][ldsw1]);
      Ap0 += BK; Ap1 += BK; Bp0 += BK; Bp1 += BK;
    }
    const u16* as = As[cur];
    const u16* bs = Bs[cur];
    bf16x8 af[4], bfr[4];
#pragma unroll
    for (int m = 0; m < 4; m++)
      af[m] = *(const bf16x8*)&as[(wr * 64 + m * 16 + fr) * BK + fgk];
#pragma unroll
    for (int n = 0; n < 4; n++)
      bfr[n] = *(const bf16x8*)&bs[(wc * 64 + n * 16 + fr) * BK + fgk];
#pragma unroll
    for (int m = 0; m < 4; m++)
#pragma unroll
      for (int n = 0; n < 4; n++)
        acc[m][n] = __builtin_amdgcn_mfma_f32_16x16x32_bf16(af[m], bfr[n], acc[m][n], 0, 0, 0);
    __syncthreads();
    cur = nxt;
  }

  int fg4 = (lane >> 4) * 4;
#pragma unroll
  for (int m = 0; m < 4; m++) {
#pragma unroll
    for (int j = 0; j < 4; j++) {
      int rloc = wr * 64 + m * 16 + fg4 + j;
      int rr = mbase + rloc;
      if (AMODE != 0 && rr >= Mloc) continue;
      int t = 0; float wv = 0.f;
      if (EPI == 4) { t = tok[e * NTOK + rr]; wv = wgt[e * NTOK + rr]; }
#pragma unroll
      for (int n = 0; n < 4; n++) {
        int col = nbase + wc * 64 + n * 16 + fr;
        float v = acc[m][n][j];
        if (EPI == 2) {
          outF[(size_t)rr * ldo + col] = v;
        } else {
          unsafeAtomicAdd(&outF[(size_t)t * ldo + col], v * wv);
        }
      }
    }
  }
}

// ---------------- host ----------------
extern "C" void kernel_launch(void* const* d_in, const int* in_sizes, int n_in,
                              void* d_out, int out_size, void* d_ws, size_t ws_size,
                              hipStream_t stream)
{
  const float* x   = (const float*)d_in[0];
  const float* gw  = (const float*)d_in[1];
  const float* ew1 = (const float*)d_in[2];
  const float* ew2 = (const float*)d_in[3];
  const float* ewp = (const float*)d_in[4];
  const float* sw1 = (const float*)d_in[5];
  const float* sw2 = (const float*)d_in[6];
  const float* swp = (const float*)d_in[7];
  float* out    = (float*)d_out;
  float* scores = out + (size_t)NTOK * CDIM;

  char* wsp = (char*)d_ws;
  size_t off = 0;
  auto alloc = [&](size_t bytes) -> void* {
    void* p = wsp + off; off += (bytes + 255) & ~(size_t)255; return p;
  };
  u16* xb   = (u16*)alloc((size_t)NTOK * CDIM * 2);
  // expert weights transposed, contiguous: [ew1t | ew2t | ewpt], 24 x 1024^2
  u16* eall = (u16*)alloc((size_t)24 * CDIM * FEDIM * 2);
  u16* ew1t = eall;
  u16* ew2t = eall + (size_t)8 * CDIM * FEDIM;
  u16* ewpt = eall + (size_t)16 * CDIM * FEDIM;
  // shared W1/W2 transposed contiguous: [sw1t | sw2t]
  u16* s12t = (u16*)alloc((size_t)2 * FSDIM * CDIM * 2);
  u16* sw1t = s12t;
  u16* sw2t = s12t + (size_t)FSDIM * CDIM;
  u16* swpt = (u16*)alloc((size_t)CDIM * FSDIM * 2);
  u16* hs   = (u16*)alloc((size_t)NTOK * FSDIM * 2);   // shared h (64 MB)
  u16* he   = hs;   // expert h (32 MB) ALIASES hs: hs dead before he written
  int* cnt  = (int*)alloc(256);
  int* tok  = (int*)alloc((size_t)NEXP * NTOK * 4);
  float* wgt = (float*)alloc((size_t)NEXP * NTOK * 4);
  if (off > ws_size) return;

  hipMemsetAsync(cnt, 0, 32, stream);
  gate_kernel<<<NTOK / 32, 256, 0, stream>>>(x, gw, scores, xb, cnt, tok, wgt);

  // 3 transpose launches (was 6 + prefix): expert trio (z=24), shared pair,
  // shared proj. All 64x32 tiles with short2 stores.
  transpose64_kernel<<<dim3(FEDIM/32, CDIM/64, 24), 256, 0, stream>>>(
      ew1, ew2, ewp, eall, CDIM, FEDIM, 8);
  transpose64_kernel<<<dim3(FSDIM/32, CDIM/64, 2), 256, 0, stream>>>(
      sw1, sw2, sw1, s12t, CDIM, FSDIM, 1);
  transpose64_kernel<<<dim3(CDIM/32, FSDIM/64, 1), 256, 0, stream>>>(
      swp, swp, swp, swpt, FSDIM, CDIM, 1);

  // shared FFN: fused SwiGLU (N=4096, K=1024) then proj (N=1024, K=4096)
  gemm_swiglu<0><<<dim3(FSDIM/BN, NTOK/BM, 1), 256, 0, stream>>>(
      xb, CDIM, sw1t, sw2t, 0, CDIM, NTOK, CDIM, hs, FSDIM, nullptr, nullptr);
  gemm_proj<2,0><<<dim3(CDIM/BN, NTOK/BM, 1), 256, 0, stream>>>(
      hs, FSDIM, swpt, 0, FSDIM, NTOK, FSDIM, out, CDIM, nullptr, nullptr, nullptr);

  // experts: fused SwiGLU on gathered rows, then proj with weighted scatter
  size_t estride = (size_t)FEDIM * CDIM;
  gemm_swiglu<1><<<dim3(FEDIM/BN, NTOK/BM, NEXP), 256, 0, stream>>>(
      xb, CDIM, ew1t, ew2t, estride, CDIM, 0, CDIM, he, FEDIM, cnt, tok);
  gemm_proj<4,2><<<dim3(CDIM/BN, NTOK/BM, NEXP), 256, 0, stream>>>(
      he, FEDIM, ewpt, estride, FEDIM, 0, FEDIM, out, CDIM, cnt, tok, wgt);
}